// Round 1
// baseline (73.203 us; speedup 1.0000x reference)
//
#include <hip/hip_runtime.h>

constexpr int B  = 2;
constexpr int L  = 256;
constexpr int Dd = 512;
constexpr int Hh = 256;
constexpr int Oo = 16;
constexpr int BL = B * L;

// ---------------------------------------------------------------------------
// Kernel 1: h1 = leaky(x@W1^T + b1), h2 = leaky(x@W2^T + b2)
// Block = 256 threads (one per h), handles ROWS consecutive (b,l) rows.
// x rows staged in LDS; W rows streamed from L2 (W1+W2 = 1 MB, L2-hot).
// ---------------------------------------------------------------------------
template <int ROWS>
__global__ __launch_bounds__(256) void mlp2_kernel(
    const float* __restrict__ x,
    const float* __restrict__ W1, const float* __restrict__ b1,
    const float* __restrict__ W2, const float* __restrict__ b2,
    float* __restrict__ h1, float* __restrict__ h2)
{
    __shared__ float xs[ROWS][Dd];
    const int row0 = blockIdx.x * ROWS;
    const int t = threadIdx.x;

    const float4* xg  = reinterpret_cast<const float4*>(x + (size_t)row0 * Dd);
    float4*       xsv = reinterpret_cast<float4*>(&xs[0][0]);
    #pragma unroll
    for (int k = t; k < ROWS * Dd / 4; k += 256) xsv[k] = xg[k];
    __syncthreads();

    const int h = t;  // 0..255
    const float4* w1 = reinterpret_cast<const float4*>(W1 + (size_t)h * Dd);
    const float4* w2 = reinterpret_cast<const float4*>(W2 + (size_t)h * Dd);

    float acc1[ROWS], acc2[ROWS];
    #pragma unroll
    for (int r = 0; r < ROWS; ++r) { acc1[r] = 0.f; acc2[r] = 0.f; }

    for (int k = 0; k < Dd / 4; ++k) {
        const float4 a = w1[k];
        const float4 c = w2[k];
        #pragma unroll
        for (int r = 0; r < ROWS; ++r) {
            const float4 xv = reinterpret_cast<const float4*>(xs[r])[k];
            acc1[r] += a.x * xv.x + a.y * xv.y + a.z * xv.z + a.w * xv.w;
            acc2[r] += c.x * xv.x + c.y * xv.y + c.z * xv.z + c.w * xv.w;
        }
    }

    const float bb1 = b1[h], bb2 = b2[h];
    #pragma unroll
    for (int r = 0; r < ROWS; ++r) {
        float v1 = acc1[r] + bb1; v1 = (v1 >= 0.f) ? v1 : 0.1f * v1;
        float v2 = acc2[r] + bb2; v2 = (v2 >= 0.f) ? v2 : 0.1f * v2;
        h1[(size_t)(row0 + r) * Hh + h] = v1;
        h2[(size_t)(row0 + r) * Hh + h] = v2;
    }
}

// ---------------------------------------------------------------------------
// Kernel 2: rank-O projections.
//   A [b,o,j]  = Wf1·h1[b,j] + 0.5*Wf2·h2[b,j]      (j-dependent terms)
//   Bv[b,o,i]  = -Wf1·h2[b,i] + 0.5*Wf2·h1[b,i]     (i-dependent terms)
//   D1[b,o,l]  = Wf3·h1[b,l]                        (cumsum'd later -> C)
// Stored transposed [B][O][L] so later reads are contiguous in l.
// Block = 256 threads: 16 rows x 16 outputs.
// ---------------------------------------------------------------------------
__global__ __launch_bounds__(256) void proj_kernel(
    const float* __restrict__ h1, const float* __restrict__ h2,
    const float* __restrict__ Wf,
    float* __restrict__ A_T, float* __restrict__ Bv_T, float* __restrict__ D1_T)
{
    const int t  = threadIdx.x;
    const int rl = t >> 4;       // local row 0..15
    const int o  = t & 15;       // output 0..15
    const int bl = blockIdx.x * 16 + rl;

    const float4* h1r = reinterpret_cast<const float4*>(h1 + (size_t)bl * Hh);
    const float4* h2r = reinterpret_cast<const float4*>(h2 + (size_t)bl * Hh);
    const float*  wfo = Wf + (size_t)o * (3 * Hh);
    const float4* wf1 = reinterpret_cast<const float4*>(wfo);
    const float4* wf2 = reinterpret_cast<const float4*>(wfo + Hh);
    const float4* wf3 = reinterpret_cast<const float4*>(wfo + 2 * Hh);

    float a = 0.f, bv = 0.f, d1 = 0.f;
    for (int k = 0; k < Hh / 4; ++k) {
        const float4 w1v = wf1[k], w2v = wf2[k], w3v = wf3[k];
        const float4 v1 = h1r[k], v2 = h2r[k];
        a  += (w1v.x * v1.x + w1v.y * v1.y + w1v.z * v1.z + w1v.w * v1.w)
            + 0.5f * (w2v.x * v2.x + w2v.y * v2.y + w2v.z * v2.z + w2v.w * v2.w);
        bv += -(w1v.x * v2.x + w1v.y * v2.y + w1v.z * v2.z + w1v.w * v2.w)
            + 0.5f * (w2v.x * v1.x + w2v.y * v1.y + w2v.z * v1.z + w2v.w * v1.w);
        d1 += (w3v.x * v1.x + w3v.y * v1.y + w3v.z * v1.z + w3v.w * v1.w);
    }

    const int b = bl / L, l = bl % L;
    const size_t idx = ((size_t)b * Oo + o) * L + l;
    A_T[idx]  = a;
    Bv_T[idx] = bv;
    D1_T[idx] = d1;
}

// ---------------------------------------------------------------------------
// Kernel 3: in-place cumsum of D1 over l per (b,o): C[b,o,l] = Wf3·cum[b,l]
// Only B*O = 32 sequences of length 256 — one thread each.
// ---------------------------------------------------------------------------
__global__ void cumsum_kernel(float* __restrict__ C_T)
{
    const int t = blockIdx.x * blockDim.x + threadIdx.x;
    if (t >= B * Oo) return;
    float* p = C_T + (size_t)t * L;
    float run = 0.f;
    for (int l = 0; l < L; ++l) { run += p[l]; p[l] = run; }
}

// ---------------------------------------------------------------------------
// Kernel 4: epilogue broadcast.
//   out[b,o,i,j] = A[b,o,j] + Bv[b,o,i]
//                + (C[b,o,j] - (i>0 ? C[b,o,i-1] : 0)) / ((j-i+1) + 1e-9)
//                + bf[o]
// Block = 256 threads: 4 i-rows x 64 float4 j-quads. Grid = B*O*L/4 = 2048.
// Note: at i=j+1 the numerator is exactly 0 (same stored C value), matching
// the reference's exact-zero span_sum, so the /1e-9 never amplifies error.
// ---------------------------------------------------------------------------
__global__ __launch_bounds__(256) void out_kernel(
    const float* __restrict__ A_T, const float* __restrict__ Bv_T,
    const float* __restrict__ C_T, const float* __restrict__ bf,
    float* __restrict__ out)
{
    const int blk = blockIdx.x;
    const int bo  = blk >> 6;          // b*O + o, 0..31
    const int i0  = (blk & 63) << 2;   // 4 i's per block
    const int t   = threadIdx.x;
    const int i   = i0 + (t >> 6);
    const int j0  = (t & 63) << 2;

    const float* Arow = A_T + (size_t)bo * L;
    const float* Crow = C_T + (size_t)bo * L;
    const float  bvi  = Bv_T[(size_t)bo * L + i];
    const float  cp   = (i > 0) ? Crow[i - 1] : 0.f;
    const float  base = bvi + bf[bo & (Oo - 1)];

    const float4 Av = *reinterpret_cast<const float4*>(Arow + j0);
    const float4 Cv = *reinterpret_cast<const float4*>(Crow + j0);

    float4 r;
    r.x = Av.x + base + (Cv.x - cp) / ((float)(j0 + 0 - i + 1) + 1e-9f);
    r.y = Av.y + base + (Cv.y - cp) / ((float)(j0 + 1 - i + 1) + 1e-9f);
    r.z = Av.z + base + (Cv.z - cp) / ((float)(j0 + 2 - i + 1) + 1e-9f);
    r.w = Av.w + base + (Cv.w - cp) / ((float)(j0 + 3 - i + 1) + 1e-9f);

    *reinterpret_cast<float4*>(out + ((size_t)bo * L + i) * L + j0) = r;
}

// ---------------------------------------------------------------------------
extern "C" void kernel_launch(void* const* d_in, const int* in_sizes, int n_in,
                              void* d_out, int out_size, void* d_ws, size_t ws_size,
                              hipStream_t stream)
{
    const float* x  = (const float*)d_in[0];
    const float* W1 = (const float*)d_in[1];
    const float* b1 = (const float*)d_in[2];
    const float* W2 = (const float*)d_in[3];
    const float* b2 = (const float*)d_in[4];
    const float* Wf = (const float*)d_in[5];
    const float* bf = (const float*)d_in[6];
    float* out = (float*)d_out;

    float* ws   = (float*)d_ws;
    float* h1   = ws;                    // BL*Hh = 131072 floats
    float* h2   = h1 + (size_t)BL * Hh;  // 131072
    float* A_T  = h2 + (size_t)BL * Hh;  // B*O*L = 8192
    float* Bv_T = A_T + (size_t)B * Oo * L;
    float* C_T  = Bv_T + (size_t)B * Oo * L;

    hipLaunchKernelGGL((mlp2_kernel<4>), dim3(BL / 4), dim3(256), 0, stream,
                       x, W1, b1, W2, b2, h1, h2);
    hipLaunchKernelGGL(proj_kernel, dim3(BL / 16), dim3(256), 0, stream,
                       h1, h2, Wf, A_T, Bv_T, C_T);
    hipLaunchKernelGGL(cumsum_kernel, dim3(1), dim3(64), 0, stream, C_T);
    hipLaunchKernelGGL(out_kernel, dim3(B * Oo * L / 4), dim3(256), 0, stream,
                       A_T, Bv_T, C_T, bf, out);
}

// Round 2
// 32.823 us; speedup vs baseline: 2.2302x; 2.2302x over previous
//
#include <hip/hip_runtime.h>

constexpr int B  = 2;
constexpr int L  = 256;
constexpr int Dd = 512;
constexpr int Hh = 256;
constexpr int Oo = 16;
constexpr int BL = B * L;

__device__ __forceinline__ float dot4(const float4 a, const float4 b) {
    return a.x * b.x + a.y * b.y + a.z * b.z + a.w * b.w;
}
__device__ __forceinline__ float leaky(const float v) {
    return (v >= 0.f) ? v : 0.1f * v;
}

// ---------------------------------------------------------------------------
// K1: h = leaky(x@W^T + b) for both matrices.
// grid = (BL/4 rowgroups, 2 h-halves, 2 matrices) = (128,2,2) = 512 blocks.
// block = 64 threads; thread owns h0=hg*128+2t, h0+1 (2 W rows in registers)
// x 4 rows staged in LDS (8 KB), read wave-uniform -> LDS broadcast (free).
// 8 accumulators, 32 FMA per float4 k-step.
// ---------------------------------------------------------------------------
__global__ __launch_bounds__(64) void mlp_kernel(
    const float* __restrict__ x,
    const float* __restrict__ W1, const float* __restrict__ b1,
    const float* __restrict__ W2, const float* __restrict__ b2,
    float* __restrict__ h1, float* __restrict__ h2)
{
    const int rg = blockIdx.x;           // 0..127 -> 4 rows each
    const int hg = blockIdx.y;           // 0..1   -> 128 h each
    const int m  = blockIdx.z;           // 0..1   -> matrix
    const float* __restrict__ W  = m ? W2 : W1;
    const float* __restrict__ bs = m ? b2 : b1;
    float* __restrict__ ho       = m ? h2 : h1;

    __shared__ float xs[4 * Dd];
    const int t = threadIdx.x;
    {
        const float4* xg = reinterpret_cast<const float4*>(x + (size_t)rg * 4 * Dd);
        float4* s = reinterpret_cast<float4*>(xs);
        #pragma unroll
        for (int i = 0; i < 8; ++i) s[t + 64 * i] = xg[t + 64 * i];
    }
    __syncthreads();

    const int h0 = hg * 128 + t * 2;
    const float4* wa = reinterpret_cast<const float4*>(W + (size_t)h0 * Dd);
    const float4* wb = reinterpret_cast<const float4*>(W + (size_t)(h0 + 1) * Dd);
    const float4* x0 = reinterpret_cast<const float4*>(xs);
    const float4* x1 = reinterpret_cast<const float4*>(xs + Dd);
    const float4* x2 = reinterpret_cast<const float4*>(xs + 2 * Dd);
    const float4* x3 = reinterpret_cast<const float4*>(xs + 3 * Dd);

    float a0 = 0.f, a1 = 0.f, a2 = 0.f, a3 = 0.f;
    float c0 = 0.f, c1 = 0.f, c2 = 0.f, c3 = 0.f;

    #pragma unroll 4
    for (int k = 0; k < Dd / 4; ++k) {
        const float4 A = wa[k];
        const float4 C = wb[k];
        const float4 p = x0[k], q = x1[k], r = x2[k], s = x3[k];
        a0 += dot4(A, p); a1 += dot4(A, q); a2 += dot4(A, r); a3 += dot4(A, s);
        c0 += dot4(C, p); c1 += dot4(C, q); c2 += dot4(C, r); c3 += dot4(C, s);
    }

    const float ba = bs[h0], bb = bs[h0 + 1];
    const int row0 = rg * 4;
    ho[(size_t)(row0 + 0) * Hh + h0]     = leaky(a0 + ba);
    ho[(size_t)(row0 + 1) * Hh + h0]     = leaky(a1 + ba);
    ho[(size_t)(row0 + 2) * Hh + h0]     = leaky(a2 + ba);
    ho[(size_t)(row0 + 3) * Hh + h0]     = leaky(a3 + ba);
    ho[(size_t)(row0 + 0) * Hh + h0 + 1] = leaky(c0 + bb);
    ho[(size_t)(row0 + 1) * Hh + h0 + 1] = leaky(c1 + bb);
    ho[(size_t)(row0 + 2) * Hh + h0 + 1] = leaky(c2 + bb);
    ho[(size_t)(row0 + 3) * Hh + h0 + 1] = leaky(c3 + bb);
}

// ---------------------------------------------------------------------------
// K2: rank-O projections (A, Bv, D1) stored [B][O][L].
// grid = 256 blocks x 128 threads; block = 2 rows; lane = (o 0..15, kq 0..3);
// each thread reduces a 64-wide K slice, then __shfl_xor(16/32) combine.
// ---------------------------------------------------------------------------
__global__ __launch_bounds__(128) void proj_kernel(
    const float* __restrict__ h1, const float* __restrict__ h2,
    const float* __restrict__ Wf,
    float* __restrict__ A_T, float* __restrict__ Bv_T, float* __restrict__ D1_T)
{
    const int t    = threadIdx.x;
    const int bl   = blockIdx.x * 2 + (t >> 6);
    const int lane = t & 63;
    const int o    = lane & 15;
    const int kq   = lane >> 4;

    const float4* h1r = reinterpret_cast<const float4*>(h1 + (size_t)bl * Hh + kq * 64);
    const float4* h2r = reinterpret_cast<const float4*>(h2 + (size_t)bl * Hh + kq * 64);
    const float*  wfo = Wf + (size_t)o * (3 * Hh) + kq * 64;
    const float4* wf1 = reinterpret_cast<const float4*>(wfo);
    const float4* wf2 = reinterpret_cast<const float4*>(wfo + Hh);
    const float4* wf3 = reinterpret_cast<const float4*>(wfo + 2 * Hh);

    float a = 0.f, bv = 0.f, d1 = 0.f;
    #pragma unroll
    for (int k = 0; k < 16; ++k) {
        const float4 w1v = wf1[k], w2v = wf2[k], w3v = wf3[k];
        const float4 v1 = h1r[k], v2 = h2r[k];
        a  += dot4(w1v, v1) + 0.5f * dot4(w2v, v2);
        bv += 0.5f * dot4(w2v, v1) - dot4(w1v, v2);
        d1 += dot4(w3v, v1);
    }
    a  += __shfl_xor(a, 16);  a  += __shfl_xor(a, 32);
    bv += __shfl_xor(bv, 16); bv += __shfl_xor(bv, 32);
    d1 += __shfl_xor(d1, 16); d1 += __shfl_xor(d1, 32);

    if (kq == 0) {
        const int b = bl >> 8, l = bl & 255;
        const size_t idx = ((size_t)(b * Oo + o)) * L + l;
        A_T[idx]  = a;
        Bv_T[idx] = bv;
        D1_T[idx] = d1;
    }
}

// ---------------------------------------------------------------------------
// K3: fused cumsum + epilogue.
// grid = 32 bo x 8 i-chunks = 256 blocks, 256 threads.
// Each block scans its D1 row (Hillis-Steele in LDS, 8 steps) -> C[l], then
// writes a 32 x 256 output tile: out[bo,i,j] = A[j] + Bv[i] + bf[o]
//   + (C[j] - C[i-1]) / (j-i+1 + 1e-9).
// i = j+1 numerator is exactly 0 (identical LDS values), matching the
// reference's exact-zero span_sum.
// ---------------------------------------------------------------------------
__global__ __launch_bounds__(256) void out_kernel(
    const float* __restrict__ A_T, const float* __restrict__ Bv_T,
    const float* __restrict__ D1_T, const float* __restrict__ bf,
    float* __restrict__ out)
{
    const int bo = blockIdx.x >> 3;    // 0..31
    const int ig = blockIdx.x & 7;     // i-chunk of 32
    const int t  = threadIdx.x;

    __shared__ float ca[L], cb[L];
    ca[t] = D1_T[(size_t)bo * L + t];
    __syncthreads();

    float* src = ca;
    float* dst = cb;
    #pragma unroll
    for (int off = 1; off < L; off <<= 1) {
        const float s = src[t] + ((t >= off) ? src[t - off] : 0.f);
        dst[t] = s;
        __syncthreads();
        float* tmp = src; src = dst; dst = tmp;
    }
    // src[l] = inclusive prefix C[l]

    const float bfv = bf[bo & (Oo - 1)];
    const int jq = t & 63;
    const int j0 = jq * 4;
    const int iq = t >> 6;

    const float4 Av = *reinterpret_cast<const float4*>(A_T + (size_t)bo * L + j0);
    const float4 Cv = *reinterpret_cast<const float4*>(src + j0);

    #pragma unroll
    for (int ii = 0; ii < 8; ++ii) {
        const int i = ig * 32 + iq * 8 + ii;
        const float cp   = (i > 0) ? src[i - 1] : 0.f;
        const float base = Bv_T[(size_t)bo * L + i] + bfv;
        float4 r;
        r.x = Av.x + base + (Cv.x - cp) / ((float)(j0 + 0 - i + 1) + 1e-9f);
        r.y = Av.y + base + (Cv.y - cp) / ((float)(j0 + 1 - i + 1) + 1e-9f);
        r.z = Av.z + base + (Cv.z - cp) / ((float)(j0 + 2 - i + 1) + 1e-9f);
        r.w = Av.w + base + (Cv.w - cp) / ((float)(j0 + 3 - i + 1) + 1e-9f);
        *reinterpret_cast<float4*>(out + ((size_t)bo * L + i) * L + j0) = r;
    }
}

// ---------------------------------------------------------------------------
extern "C" void kernel_launch(void* const* d_in, const int* in_sizes, int n_in,
                              void* d_out, int out_size, void* d_ws, size_t ws_size,
                              hipStream_t stream)
{
    const float* x  = (const float*)d_in[0];
    const float* W1 = (const float*)d_in[1];
    const float* b1 = (const float*)d_in[2];
    const float* W2 = (const float*)d_in[3];
    const float* b2 = (const float*)d_in[4];
    const float* Wf = (const float*)d_in[5];
    const float* bf = (const float*)d_in[6];
    float* out = (float*)d_out;

    float* ws   = (float*)d_ws;
    float* h1   = ws;                        // BL*Hh = 131072 floats
    float* h2   = h1 + (size_t)BL * Hh;      // 131072
    float* A_T  = h2 + (size_t)BL * Hh;      // B*O*L = 8192
    float* Bv_T = A_T + (size_t)B * Oo * L;  // 8192
    float* D1_T = Bv_T + (size_t)B * Oo * L; // 8192

    hipLaunchKernelGGL(mlp_kernel, dim3(BL / 4, 2, 2), dim3(64), 0, stream,
                       x, W1, b1, W2, b2, h1, h2);
    hipLaunchKernelGGL(proj_kernel, dim3(BL / 2), dim3(128), 0, stream,
                       h1, h2, Wf, A_T, Bv_T, D1_T);
    hipLaunchKernelGGL(out_kernel, dim3(B * Oo * 8), dim3(256), 0, stream,
                       A_T, Bv_T, D1_T, bf, out);
}

// Round 3
// 21.896 us; speedup vs baseline: 3.3432x; 1.4990x over previous
//
#include <hip/hip_runtime.h>

constexpr int B  = 2;
constexpr int L  = 256;
constexpr int Dd = 512;
constexpr int Hh = 256;
constexpr int Oo = 16;
constexpr int BL = B * L;

__device__ __forceinline__ float dot4(const float4 a, const float4 b) {
    return a.x * b.x + a.y * b.y + a.z * b.z + a.w * b.w;
}
__device__ __forceinline__ float leaky(const float v) {
    return (v >= 0.f) ? v : 0.1f * v;
}

// ---------------------------------------------------------------------------
// K1: h = leaky(x@W^T + b), both matrices.
// grid = (64 rowsets of 8, 4 h-chunks of 64, 2 matrices) = 512 blocks, 256 thr.
// Wave = 4 h-groups x 16 k-lanes; lane owns 4 consecutive W rows, k-slice of
// 64 floats per step. W loads: 16 lanes x 16B = 256B contiguous per h-row ->
// coalesced. x-tile (8 rows, 16 KB) in LDS: k-lanes hit distinct banks,
// h-groups broadcast. Reduction over k-lanes via shfl_xor(1/2/4/8).
// Per lane: 1024 FMA vs 64 LDS b128 + 32 coalesced W b128.
// ---------------------------------------------------------------------------
__global__ __launch_bounds__(256) void mlp_kernel(
    const float* __restrict__ x,
    const float* __restrict__ W1, const float* __restrict__ b1,
    const float* __restrict__ W2, const float* __restrict__ b2,
    float* __restrict__ h1, float* __restrict__ h2)
{
    const int rs = blockIdx.x;   // rowset: 8 bl-rows
    const int hc = blockIdx.y;   // h-chunk: 64 h
    const int m  = blockIdx.z;
    const float* __restrict__ W  = m ? W2 : W1;
    const float* __restrict__ bb = m ? b2 : b1;
    float* __restrict__ ho       = m ? h2 : h1;

    __shared__ float xs[8 * Dd];
    const int t = threadIdx.x;
    {
        const float4* xg = reinterpret_cast<const float4*>(x + (size_t)rs * 8 * Dd);
        float4* s4 = reinterpret_cast<float4*>(xs);
        #pragma unroll
        for (int i = 0; i < 4; ++i) s4[t + 256 * i] = xg[t + 256 * i];
    }
    __syncthreads();

    const int wave = t >> 6, lane = t & 63, g = lane >> 4, kl = lane & 15;
    const int h0 = hc * 64 + wave * 16 + g * 4;

    const float4* w0 = reinterpret_cast<const float4*>(W + (size_t)(h0 + 0) * Dd);
    const float4* w1 = reinterpret_cast<const float4*>(W + (size_t)(h0 + 1) * Dd);
    const float4* w2 = reinterpret_cast<const float4*>(W + (size_t)(h0 + 2) * Dd);
    const float4* w3 = reinterpret_cast<const float4*>(W + (size_t)(h0 + 3) * Dd);
    const float4* xs4 = reinterpret_cast<const float4*>(xs);

    float acc[8][4];
    #pragma unroll
    for (int r = 0; r < 8; ++r)
        #pragma unroll
        for (int j = 0; j < 4; ++j) acc[r][j] = 0.f;

    #pragma unroll
    for (int s = 0; s < 8; ++s) {
        const int ko = s * 16 + kl;
        const float4 a = w0[ko], b_ = w1[ko], c = w2[ko], d = w3[ko];
        #pragma unroll
        for (int r = 0; r < 8; ++r) {
            const float4 xv = xs4[r * 128 + ko];
            acc[r][0] += dot4(xv, a);
            acc[r][1] += dot4(xv, b_);
            acc[r][2] += dot4(xv, c);
            acc[r][3] += dot4(xv, d);
        }
    }

    #pragma unroll
    for (int r = 0; r < 8; ++r)
        #pragma unroll
        for (int j = 0; j < 4; ++j) {
            float v = acc[r][j];
            v += __shfl_xor(v, 1); v += __shfl_xor(v, 2);
            v += __shfl_xor(v, 4); v += __shfl_xor(v, 8);
            acc[r][j] = v;
        }

    if (kl == 0) {
        const float4 bv = *reinterpret_cast<const float4*>(bb + h0);
        const int row0 = rs * 8;
        #pragma unroll
        for (int r = 0; r < 8; ++r) {
            float4 o;
            o.x = leaky(acc[r][0] + bv.x);
            o.y = leaky(acc[r][1] + bv.y);
            o.z = leaky(acc[r][2] + bv.z);
            o.w = leaky(acc[r][3] + bv.w);
            *reinterpret_cast<float4*>(ho + (size_t)(row0 + r) * Hh + h0) = o;
        }
    }
}

// ---------------------------------------------------------------------------
// K2: rank-O projections, one bl-row per block (grid 512, 256 thr).
// Wave = 4 o x 16 k-lanes: Wf loads coalesced (256B runs); h1/h2 read direct
// from global, k-lanes coalesced + o-groups L1-broadcast.
//   A [b,o,l] =  Wf1.h1 + 0.5*Wf2.h2
//   Bv[b,o,l] = 0.5*Wf2.h1 - Wf1.h2
//   D1[b,o,l] =  Wf3.h1
// ---------------------------------------------------------------------------
__global__ __launch_bounds__(256) void proj_kernel(
    const float* __restrict__ h1, const float* __restrict__ h2,
    const float* __restrict__ Wf,
    float* __restrict__ A_T, float* __restrict__ Bv_T, float* __restrict__ D1_T)
{
    const int bl = blockIdx.x;
    const int t = threadIdx.x, wave = t >> 6, lane = t & 63;
    const int og = lane >> 4, kl = lane & 15;
    const int o = wave * 4 + og;

    const float4* wf1 = reinterpret_cast<const float4*>(Wf + (size_t)o * (3 * Hh));
    const float4* wf2 = wf1 + Hh / 4;
    const float4* wf3 = wf1 + Hh / 2;
    const float4* v1p = reinterpret_cast<const float4*>(h1 + (size_t)bl * Hh);
    const float4* v2p = reinterpret_cast<const float4*>(h2 + (size_t)bl * Hh);

    float a = 0.f, bv = 0.f, d1 = 0.f;
    #pragma unroll
    for (int s = 0; s < 4; ++s) {
        const int ko = s * 16 + kl;
        const float4 W1v = wf1[ko], W2v = wf2[ko], W3v = wf3[ko];
        const float4 v1 = v1p[ko], v2 = v2p[ko];
        a  += dot4(W1v, v1) + 0.5f * dot4(W2v, v2);
        bv += 0.5f * dot4(W2v, v1) - dot4(W1v, v2);
        d1 += dot4(W3v, v1);
    }
    a  += __shfl_xor(a, 1);  a  += __shfl_xor(a, 2);  a  += __shfl_xor(a, 4);  a  += __shfl_xor(a, 8);
    bv += __shfl_xor(bv, 1); bv += __shfl_xor(bv, 2); bv += __shfl_xor(bv, 4); bv += __shfl_xor(bv, 8);
    d1 += __shfl_xor(d1, 1); d1 += __shfl_xor(d1, 2); d1 += __shfl_xor(d1, 4); d1 += __shfl_xor(d1, 8);

    if (kl == 0) {
        const int b = bl >> 8, l = bl & 255;
        const size_t idx = ((size_t)(b * Oo + o)) * L + l;
        A_T[idx]  = a;
        Bv_T[idx] = bv;
        D1_T[idx] = d1;
    }
}

// ---------------------------------------------------------------------------
// K3: fused cumsum + epilogue. grid = 32 bo x 16 i-chunks = 512 blocks.
// Per block: Hillis-Steele scan of the 256-float D1 row in LDS -> C[l], then
// write a 16 x 256 tile:
//   out[bo,i,j] = A[j] + Bv[i] + bf[o] + (C[j]-C[i-1])/(j-i+1+1e-9)
// i = j+1 numerator is exactly 0 (identical LDS values) -> no 1e9 blowup.
// ---------------------------------------------------------------------------
__global__ __launch_bounds__(256) void out_kernel(
    const float* __restrict__ A_T, const float* __restrict__ Bv_T,
    const float* __restrict__ D1_T, const float* __restrict__ bf,
    float* __restrict__ out)
{
    const int bo = blockIdx.x >> 4;    // 0..31
    const int ig = blockIdx.x & 15;    // i-chunk of 16
    const int t  = threadIdx.x;

    __shared__ float ca[L], cb[L];
    ca[t] = D1_T[(size_t)bo * L + t];
    __syncthreads();

    float* src = ca;
    float* dst = cb;
    #pragma unroll
    for (int off = 1; off < L; off <<= 1) {
        const float s = src[t] + ((t >= off) ? src[t - off] : 0.f);
        dst[t] = s;
        __syncthreads();
        float* tmp = src; src = dst; dst = tmp;
    }
    // src[l] = inclusive prefix C[l]

    const float bfv = bf[bo & (Oo - 1)];
    const int j0 = (t & 63) * 4;
    const int is = t >> 6;

    const float4 Av = *reinterpret_cast<const float4*>(A_T + (size_t)bo * L + j0);
    const float4 Cv = *reinterpret_cast<const float4*>(src + j0);

    #pragma unroll
    for (int ii = 0; ii < 4; ++ii) {
        const int i = ig * 16 + is * 4 + ii;
        const float cp   = (i > 0) ? src[i - 1] : 0.f;
        const float base = Bv_T[(size_t)bo * L + i] + bfv;
        float4 r;
        r.x = Av.x + base + (Cv.x - cp) / ((float)(j0 + 0 - i + 1) + 1e-9f);
        r.y = Av.y + base + (Cv.y - cp) / ((float)(j0 + 1 - i + 1) + 1e-9f);
        r.z = Av.z + base + (Cv.z - cp) / ((float)(j0 + 2 - i + 1) + 1e-9f);
        r.w = Av.w + base + (Cv.w - cp) / ((float)(j0 + 3 - i + 1) + 1e-9f);
        *reinterpret_cast<float4*>(out + ((size_t)bo * L + i) * L + j0) = r;
    }
}

// ---------------------------------------------------------------------------
extern "C" void kernel_launch(void* const* d_in, const int* in_sizes, int n_in,
                              void* d_out, int out_size, void* d_ws, size_t ws_size,
                              hipStream_t stream)
{
    const float* x  = (const float*)d_in[0];
    const float* W1 = (const float*)d_in[1];
    const float* b1 = (const float*)d_in[2];
    const float* W2 = (const float*)d_in[3];
    const float* b2 = (const float*)d_in[4];
    const float* Wf = (const float*)d_in[5];
    const float* bf = (const float*)d_in[6];
    float* out = (float*)d_out;

    float* ws   = (float*)d_ws;
    float* h1   = ws;                        // BL*Hh
    float* h2   = h1 + (size_t)BL * Hh;
    float* A_T  = h2 + (size_t)BL * Hh;      // B*O*L
    float* Bv_T = A_T + (size_t)B * Oo * L;
    float* D1_T = Bv_T + (size_t)B * Oo * L;

    hipLaunchKernelGGL(mlp_kernel, dim3(BL / 8, 4, 2), dim3(256), 0, stream,
                       x, W1, b1, W2, b2, h1, h2);
    hipLaunchKernelGGL(proj_kernel, dim3(BL), dim3(256), 0, stream,
                       h1, h2, Wf, A_T, Bv_T, D1_T);
    hipLaunchKernelGGL(out_kernel, dim3(B * Oo * 16), dim3(256), 0, stream,
                       A_T, Bv_T, D1_T, bf, out);
}